// Round 6
// baseline (94.498 us; speedup 1.0000x reference)
//
#include <hip/hip_runtime.h>
#include <hip/hip_bf16.h>

// Problem: B=4, N=512, D=1024, H=256. Inputs fp32, OUTPUT fp32.
//   o[b,n,h]     = sum_d x[b,n,d]*W1[h,d] + b1[h]                  (2048x256, K=1024)
//   out[b,i,j,c] = sum_h (o[b,i,h]*W2[c,h]) * o[b,j,h] + b2[c]     (per b,c: 512x512, K=256)
//
// R16 = R11 skeleton with the P round-trip + s1_reduce deleted via fp32 atomics:
//   Model from R11-R15: dur ~= 43us ws-poison fill + kernel traffic + ~2.5us/dispatch.
//   - s1_gemm: R11 staging verbatim (LD=72, in-kernel cvt); epilogue atomically
//     adds fp32 acc into o_acc[2048][256] (2 MB, L2/LLC-resident) instead of
//     storing 8 MB bf16 partials. 8-way contention per address only.
//   - stage2: R11 structure; operands built from o_acc on the fly:
//     j-LDS = bf16(acc+b1); i-frags a0/a1 = bf16(bf2f(bf16(acc+b1))*W2[c]),
//     pre-built into 8 statically-indexed register frags before the MFMA loop.
//   - hipMemsetAsync zeroes o_acc (capturable; replaces the s1_reduce dispatch).
//   Numerics: exact fp32 sum (vs bf16 partial sums) -> absmax ~0.031 expected.

typedef __attribute__((ext_vector_type(8))) short bf16x8;   // 8 bf16 = 4 VGPRs
typedef __attribute__((ext_vector_type(4))) short bf16x4;   // 4 bf16 = 2 VGPRs
typedef __attribute__((ext_vector_type(4))) float f32x4;
typedef __attribute__((ext_vector_type(2))) float f32x2;

__device__ __forceinline__ unsigned short f2bf(float f) {
    __hip_bfloat16 h = __float2bfloat16(f);   // RNE
    unsigned short s;
    __builtin_memcpy(&s, &h, 2);
    return s;
}

__device__ __forceinline__ float bf2f(unsigned short b) {
    unsigned int u = ((unsigned int)b) << 16;
    float f;
    __builtin_memcpy(&f, &u, 4);
    return f;
}

__device__ __forceinline__ bf16x4 cvt4(f32x4 v) {
    bf16x4 r;
    r[0] = (short)f2bf(v[0]); r[1] = (short)f2bf(v[1]);
    r[2] = (short)f2bf(v[2]); r[3] = (short)f2bf(v[3]);
    return r;
}

// ---------------- Stage 1: split-K(8) GEMM -> fp32 atomic accumulate ----------------
#define S1_LD 72

__global__ __launch_bounds__(256) void s1_gemm(
    const float* __restrict__ x,        // [2048][1024]
    const float* __restrict__ W1,       // [256][1024]
    float* __restrict__ oacc)           // [2048][256] f32, pre-zeroed
{
    __shared__ unsigned short xs[32 * S1_LD];    // 4608 B
    __shared__ unsigned short ws_[256 * S1_LD];  // 36864 B
    const int tid  = threadIdx.x;
    const int lane = tid & 63;
    const int wave = tid >> 6;
    const int kT = blockIdx.x & 7;
    const int mT = blockIdx.x >> 3;              // 0..63, 32 rows each
    const int l15 = lane & 15;
    const int quad = lane >> 4;

    f32x4 acc[2][4];
    #pragma unroll
    for (int f = 0; f < 2; ++f)
        #pragma unroll
        for (int g = 0; g < 4; ++g)
            acc[f][g] = (f32x4){0.f, 0.f, 0.f, 0.f};

    for (int p = 0; p < 2; ++p) {                // two 64-wide K phases
        const int k0 = kT * 128 + p * 64;
        if (p) __syncthreads();

        #pragma unroll
        for (int i = 0; i < 2; ++i) {            // x tile: 32x64
            const int idx = i * 256 + tid;
            const int row = idx >> 4;
            const int c4  = idx & 15;
            f32x4 v = *(const f32x4*)(x + (mT * 32 + row) * 1024 + k0 + c4 * 4);
            *(bf16x4*)(&xs[row * S1_LD + c4 * 4]) = cvt4(v);
        }
        #pragma unroll 8
        for (int i = 0; i < 16; ++i) {           // W1 tile: 256x64
            const int idx = i * 256 + tid;
            const int row = idx >> 4;
            const int c4  = idx & 15;
            f32x4 v = *(const f32x4*)(W1 + row * 1024 + k0 + c4 * 4);
            *(bf16x4*)(&ws_[row * S1_LD + c4 * 4]) = cvt4(v);
        }
        __syncthreads();

        #pragma unroll
        for (int s = 0; s < 2; ++s) {
            bf16x8 a[2], b[4];
            #pragma unroll
            for (int f = 0; f < 2; ++f)
                a[f] = *(const bf16x8*)(&xs[(f * 16 + l15) * S1_LD + s * 32 + quad * 8]);
            #pragma unroll
            for (int g = 0; g < 4; ++g)
                b[g] = *(const bf16x8*)(&ws_[(wave * 64 + g * 16 + l15) * S1_LD + s * 32 + quad * 8]);
            #pragma unroll
            for (int f = 0; f < 2; ++f)
                #pragma unroll
                for (int g = 0; g < 4; ++g)
                    acc[f][g] = __builtin_amdgcn_mfma_f32_16x16x32_bf16(a[f], b[g], acc[f][g], 0, 0, 0);
        }
    }

    // Epilogue: device-scope fp32 atomic add (HW global_atomic_add_f32).
    #pragma unroll
    for (int f = 0; f < 2; ++f) {
        #pragma unroll
        for (int g = 0; g < 4; ++g) {
            const int h = wave * 64 + g * 16 + l15;
            #pragma unroll
            for (int r = 0; r < 4; ++r) {
                const int m = mT * 32 + f * 16 + quad * 4 + r;
                __hip_atomic_fetch_add(&oacc[m * 256 + h], acc[f][g][r],
                                       __ATOMIC_RELAXED, __HIP_MEMORY_SCOPE_AGENT);
            }
        }
    }
}

// ---------------- Stage 2: 64x64 supertile, 8 waves; operands from o_acc ----------------
#define S2_LD 264   // shorts per LDS row (256 + 8 pad); 64*264*2 = 33792 B

__global__ __launch_bounds__(512) void stage2_kernel(
    const float* __restrict__ oacc,          // [2048][256] f32 (sum, no b1)
    const float* __restrict__ b1,            // [256]
    const float* __restrict__ W2,            // [2][256]
    const float* __restrict__ b2,            // [2]
    float* __restrict__ out)                 // [4][512][512][2] fp32
{
    __shared__ unsigned short js[64 * S2_LD];
    const int tid  = threadIdx.x;
    const int lane = tid & 63;
    const int wave = tid >> 6;          // 0..7
    const int blk  = blockIdx.x;        // 0..255
    const int b  = blk >> 6;            // 4
    const int iS = (blk >> 3) & 7;      // 8
    const int jS = blk & 7;             // 8
    const int l15 = lane & 15;
    const int quad = lane >> 4;
    const int wi = wave & 3;            // i 16-band within the 64-row supertile
    const int wj = wave >> 2;           // j 32-half within the 64-col supertile

    // j-stage: o_bf16 = bf16(acc + b1) -> LDS. 64 rows x 256 f32 = 4096 f32x4.
    const float* jb = oacc + (b * 512 + jS * 64) * 256;
    #pragma unroll
    for (int i = 0; i < 8; ++i) {
        const int idx = i * 512 + tid;       // row = idx>>6, 64 f32x4-chunks per row
        const int row = idx >> 6;
        const int c4  = idx & 63;
        f32x4 v  = *(const f32x4*)(jb + row * 256 + c4 * 4);
        f32x4 bb = *(const f32x4*)(b1 + c4 * 4);
        bf16x4 r;
        r[0] = (short)f2bf(v[0] + bb[0]); r[1] = (short)f2bf(v[1] + bb[1]);
        r[2] = (short)f2bf(v[2] + bb[2]); r[3] = (short)f2bf(v[3] + bb[3]);
        *(bf16x4*)(&js[row * S2_LD + c4 * 4]) = r;
    }

    // i-frags: a_c[s] = bf16(bf2f(bf16(acc+b1)) * W2[c]) — statically indexed regs.
    const int irow = iS * 64 + wi * 16 + l15;
    const float* ib = oacc + (b * 512 + irow) * 256;
    bf16x8 a0s[8], a1s[8];
    #pragma unroll
    for (int s = 0; s < 8; ++s) {
        const int c = s * 32 + quad * 8;
        f32x4 v0  = *(const f32x4*)(ib + c);
        f32x4 v1  = *(const f32x4*)(ib + c + 4);
        f32x4 bb0 = *(const f32x4*)(b1 + c);
        f32x4 bb1 = *(const f32x4*)(b1 + c + 4);
        f32x4 w00 = *(const f32x4*)(W2 + c);
        f32x4 w01 = *(const f32x4*)(W2 + c + 4);
        f32x4 w10 = *(const f32x4*)(W2 + 256 + c);
        f32x4 w11 = *(const f32x4*)(W2 + 256 + c + 4);
        #pragma unroll
        for (int e = 0; e < 4; ++e) {
            const float of0 = bf2f(f2bf(v0[e] + bb0[e]));
            const float of1 = bf2f(f2bf(v1[e] + bb1[e]));
            a0s[s][e]     = (short)f2bf(of0 * w00[e]);
            a1s[s][e]     = (short)f2bf(of0 * w10[e]);
            a0s[s][4 + e] = (short)f2bf(of1 * w01[e]);
            a1s[s][4 + e] = (short)f2bf(of1 * w11[e]);
        }
    }
    __syncthreads();

    f32x4 acc0[2], acc1[2];
    #pragma unroll
    for (int g = 0; g < 2; ++g) {
        acc0[g] = (f32x4){0.f, 0.f, 0.f, 0.f};
        acc1[g] = (f32x4){0.f, 0.f, 0.f, 0.f};
    }

    #pragma unroll
    for (int s = 0; s < 8; ++s) {
        const int k = s * 32;
        #pragma unroll
        for (int g = 0; g < 2; ++g) {
            bf16x8 bj = *(const bf16x8*)(&js[(wj * 32 + g * 16 + l15) * S2_LD + k + quad * 8]);
            acc0[g] = __builtin_amdgcn_mfma_f32_16x16x32_bf16(a0s[s], bj, acc0[g], 0, 0, 0);
            acc1[g] = __builtin_amdgcn_mfma_f32_16x16x32_bf16(a1s[s], bj, acc1[g], 0, 0, 0);
        }
    }

    const float bias0 = b2[0];
    const float bias1 = b2[1];
    #pragma unroll
    for (int g = 0; g < 2; ++g) {
        const int j = jS * 64 + wj * 32 + g * 16 + l15;      // n-index = lane&15
        #pragma unroll
        for (int r = 0; r < 4; ++r) {
            const int i = iS * 64 + wi * 16 + quad * 4 + r;  // m-index
            f32x2 v;
            v[0] = acc0[g][r] + bias0;
            v[1] = acc1[g][r] + bias1;
            *(f32x2*)(out + (((b * 512 + i) * 512) + j) * 2) = v;
        }
    }
}

extern "C" void kernel_launch(void* const* d_in, const int* in_sizes, int n_in,
                              void* d_out, int out_size, void* d_ws, size_t ws_size,
                              hipStream_t stream) {
    const float* x  = (const float*)d_in[0];   // [4,512,1024] fp32
    const float* W1 = (const float*)d_in[1];   // [256,1024] fp32
    const float* b1 = (const float*)d_in[2];   // [256] fp32
    const float* W2 = (const float*)d_in[3];   // [2,256] fp32
    const float* b2 = (const float*)d_in[4];   // [2] fp32
    float* out = (float*)d_out;                // [4,512,512,2] fp32

    // ws layout: o_acc f32 [2048][256] @ 0 (2 MB)
    float* oacc = (float*)d_ws;

    hipMemsetAsync(oacc, 0, 2048 * 256 * sizeof(float), stream);
    s1_gemm      <<<512, 256, 0, stream>>>(x, W1, oacc);
    stage2_kernel<<<256, 512, 0, stream>>>(oacc, b1, W2, b2, out);
}